// Round 1
// 768.202 us; speedup vs baseline: 1.0513x; 1.0513x over previous
//
#include <hip/hip_runtime.h>
#include <hip/hip_bf16.h>
#include <math.h>

// ---------------------------------------------------------------------------
// RhoVanillaVAE forward on gfx950.
// B=16384, DATA_DIM=4096, Z=512, H=400 (padded to 512 everywhere).
// R2: all GEMMs in fp16 (mfma_f32_16x16x32_f16).
// R3: GEMM K-loop restructured to double-buffered prefetch (T3-minimum):
//     stage tile k+1 into buf^1 BEFORE computing tile k, single
//     __syncthreads per K-step (its implicit vmcnt(0) drain is now covered
//     by ~500 cyc of ds_read+MFMA instead of fully exposed). Old structure
//     exposed a full HBM round-trip every iteration (MfmaUtil 11%).
//     Also: XCD-chunked block swizzle (m157 form; all grids %8==0) so the
//     4 n-blocks sharing an A-panel hit the same XCD L2 (FETCH 529->~300MB).
// Pipeline: pack weights (fp16, transposed [N][K]) -> GEMM1 (x fp32 -> relu h1 f16)
// -> head matvec (rho/logs/std) -> GEMM2 (mu fp32) -> zscan (cumsum -> z f16)
// -> GEMM3 (relu h3 f16) -> GEMM4 (sigmoid recon fp32).
// GEMM core: 128x128 block tile, 4 waves, 4x4x(16x16x32) MFMA frags per wave,
// BK=32, global_load_lds(16B) staging with XOR chunk swizzle so frag
// ds_read_b128s are 2-way-bank (free) instead of 4/8-way.
// ---------------------------------------------------------------------------

using f16x8 = __attribute__((ext_vector_type(8))) _Float16;
using f32x4 = __attribute__((ext_vector_type(4))) float;

#define TB   16384
#define DDIM 4096
#define ZD   512
#define HP   512   // padded H
#define HLOG 400

static constexpr size_t MU_OFF   = (size_t)TB * DDIM;          // 67108864
static constexpr size_t RHO_OFF  = MU_OFF + (size_t)TB * ZD;   // 75497472
static constexpr size_t LOGS_OFF = RHO_OFF + TB;               // 75513856

// workspace byte offsets
static constexpr size_t O_W1T  = 0;                                  // 512*4096*2 = 4 MiB
static constexpr size_t O_W21T = O_W1T  + (size_t)HP * DDIM * 2;
static constexpr size_t O_W3T  = O_W21T + (size_t)HP * HP * 2;
static constexpr size_t O_W4T  = O_W3T  + (size_t)HP * HP * 2;
static constexpr size_t O_H1P  = O_W4T  + (size_t)DDIM * HP * 2;
static constexpr size_t O_ZA   = O_H1P  + (size_t)TB * HP * 2;
static constexpr size_t O_STD  = O_ZA   + (size_t)TB * ZD * 2;
// end ~ 41 MiB

__device__ __forceinline__ void async_load16(const void* g, void* l) {
  __builtin_amdgcn_global_load_lds(
      (const __attribute__((address_space(1))) unsigned int*)g,
      (__attribute__((address_space(3))) unsigned int*)l, 16, 0, 0);
}

// ---------------------------------------------------------------------------
// Weight pack: dst[n*ds + k] = (k<R && n<C) ? (fp16)src[k*C+n] : 0
// Jobs selected by blockIdx.x range (single launch).
// ---------------------------------------------------------------------------
__global__ __launch_bounds__(256) void pack_all(
    const float* __restrict__ W1, const float* __restrict__ W21,
    const float* __restrict__ W3, const float* __restrict__ W4,
    _Float16* __restrict__ W1t, _Float16* __restrict__ W21t,
    _Float16* __restrict__ W3t, _Float16* __restrict__ W4t)
{
  __shared__ float T[32][33];
  int bx = blockIdx.x;
  const float* src; _Float16* dst; int R, C, ds, tk;
  if (bx < 2048)      { src = W1;  dst = W1t;  R = 4096; C = 400;  ds = 4096; tk = 128; }
  else if (bx < 2304) { src = W21; dst = W21t; R = 400;  C = 512;  ds = 512;  tk = 16; bx -= 2048; }
  else if (bx < 2560) { src = W3;  dst = W3t;  R = 512;  C = 400;  ds = 512;  tk = 16; bx -= 2304; }
  else                { src = W4;  dst = W4t;  R = 400;  C = 4096; ds = 512;  tk = 16; bx -= 2560; }
  int tki = bx % tk, tni = bx / tk;
  int tid = threadIdx.x;
#pragma unroll
  for (int it = 0; it < 4; ++it) {
    int idx = it * 256 + tid;
    int i = idx >> 5, j = idx & 31;
    int k = tki * 32 + i, n = tni * 32 + j;
    float val = 0.f;
    if (k < R && n < C) val = src[(size_t)k * C + n];
    T[i][j] = val;
  }
  __syncthreads();
#pragma unroll
  for (int it = 0; it < 4; ++it) {
    int idx = it * 256 + tid;
    int i = idx >> 5, j = idx & 31;
    int n = tni * 32 + i, k = tki * 32 + j;
    dst[(size_t)n * ds + k] = (_Float16)T[j][i];
  }
}

// ---------------------------------------------------------------------------
// GEMM: C[M x Npad] = A[M x K] @ Bt[Npad x K]^T, M mult of 128, Npad mult of
// 128, K mult of 64. AF32: A is fp32 (converted to fp16 at frag load).
// EPI 0: relu -> fp16 (cols >= Nlog forced to 0); 1: +bias -> fp32;
// 2: sigmoid -> fp32.
// Double-buffered: tile k+1 staged while tile k computes; one barrier/iter.
// ---------------------------------------------------------------------------
template <int AF32, int EPI>
__global__ __launch_bounds__(256, 2) void gemm_k(
    const void* __restrict__ Av, const _Float16* __restrict__ Bt,
    const float* __restrict__ bias, void* __restrict__ Cv,
    int Nlog, int K, int lda, int ldc)
{
  __shared__ _Float16 Bs[2][128 * 32];
  __shared__ float    As_f[AF32 ? 2 * 128 * 32 : 8];
  __shared__ _Float16 As_h[AF32 ? 8 : 2 * 128 * 32];

  const int tid  = threadIdx.x;
  const int lane = tid & 63;
  const int wave = tid >> 6;
  const int quad = lane >> 4;
  const int l15  = lane & 15;
  const int wm   = wave >> 1;
  const int wn   = wave & 1;

  // XCD-chunked swizzle: consecutive dispatch ids round-robin XCDs; remap so
  // each XCD owns a contiguous sb-range (all n-blocks of a contiguous m-range
  // -> A-panel fetched into ONE L2). Valid since all grids here are %8==0.
  const int gx  = gridDim.x;
  const int nwg = gx * gridDim.y;
  const int lb  = blockIdx.y * gx + blockIdx.x;
  int sb = lb;
  if ((nwg & 7) == 0) sb = (lb & 7) * (nwg >> 3) + (lb >> 3);
  const int mBase = (sb / gx) * 128;
  const int nBase = (sb % gx) * 128;

  const float*    Af = (const float*)Av;
  const _Float16* Ah = (const _Float16*)Av;

  f32x4 acc[4][4];
#pragma unroll
  for (int i = 0; i < 4; ++i)
#pragma unroll
    for (int j = 0; j < 4; ++j)
      acc[i][j] = (f32x4){0.f, 0.f, 0.f, 0.f};

  // stage tile (k0) into buffer buf. B: [128 n][32 k] f16, chunk-XOR swizzled.
  auto stage = [&](int buf, int k0) {
#pragma unroll
    for (int is = 0; is < 2; ++is) {
      int f = is * 256 + tid;
      int n = f >> 2, p = f & 3;
      int c = p ^ ((n >> 1) & 3);
      async_load16(Bt + (size_t)(nBase + n) * K + k0 + c * 8,
                   &Bs[buf][(is * 256 + wave * 64) * 8]);
    }
    if constexpr (AF32) {
      // A tile [128 m][32 k] fp32: 8 chunks/row, swizzled by m&7
#pragma unroll
      for (int is = 0; is < 4; ++is) {
        int f = is * 256 + tid;
        int m = f >> 3, p = f & 7;
        int c = p ^ (m & 7);
        async_load16(Af + (size_t)(mBase + m) * lda + k0 + c * 4,
                     &As_f[buf * (128 * 32) + (is * 256 + wave * 64) * 4]);
      }
    } else {
#pragma unroll
      for (int is = 0; is < 2; ++is) {
        int f = is * 256 + tid;
        int m = f >> 2, p = f & 3;
        int c = p ^ ((m >> 1) & 3);
        async_load16(Ah + (size_t)(mBase + m) * lda + k0 + c * 8,
                     &As_h[buf * (128 * 32) + (is * 256 + wave * 64) * 8]);
      }
    }
  };

  // one K-step: prefetch (kk+32) into buf^1, compute tile (kk) from buf.
  // Single __syncthreads at end: its implicit vmcnt(0) drain waits on the
  // prefetch AFTER the compute covered most of the load latency, and orders
  // the buf^1 writes / buf reads across waves for the next step.
  auto body = [&](int buf, int kk) {
    if (kk + 32 < K) stage(buf ^ 1, kk + 32);

    f16x8 a[4], b[4];
#pragma unroll
    for (int t = 0; t < 4; ++t) {
      int n = wn * 64 + t * 16 + l15;
      b[t] = *(const f16x8*)&Bs[buf][n * 32 + ((quad ^ ((n >> 1) & 3)) * 8)];
    }
    if constexpr (AF32) {
      const float* Ab = &As_f[buf * (128 * 32)];
#pragma unroll
      for (int t = 0; t < 4; ++t) {
        int m = wm * 64 + t * 16 + l15;
        int p0 = (2 * quad) ^ (m & 7);
        f32x4 u = *(const f32x4*)&Ab[m * 32 + p0 * 4];
        f32x4 v = *(const f32x4*)&Ab[m * 32 + (p0 ^ 1) * 4];
        f16x8 av;
        av[0] = (_Float16)u[0]; av[1] = (_Float16)u[1];
        av[2] = (_Float16)u[2]; av[3] = (_Float16)u[3];
        av[4] = (_Float16)v[0]; av[5] = (_Float16)v[1];
        av[6] = (_Float16)v[2]; av[7] = (_Float16)v[3];
        a[t] = av;
      }
    } else {
      const _Float16* Ab = &As_h[buf * (128 * 32)];
#pragma unroll
      for (int t = 0; t < 4; ++t) {
        int m = wm * 64 + t * 16 + l15;
        a[t] = *(const f16x8*)&Ab[m * 32 + ((quad ^ ((m >> 1) & 3)) * 8)];
      }
    }
#pragma unroll
    for (int i = 0; i < 4; ++i)
#pragma unroll
      for (int j = 0; j < 4; ++j)
        acc[i][j] = __builtin_amdgcn_mfma_f32_16x16x32_f16(a[i], b[j], acc[i][j], 0, 0, 0);

    __syncthreads();
  };

  // prologue: fill buf 0; implicit vmcnt(0)+barrier of __syncthreads makes
  // it visible to all waves.
  stage(0, 0);
  __syncthreads();

  // K is a multiple of 64 for every call site (4096 or 512) -> unroll x2 so
  // the buffer index is a compile-time constant after inlining.
  for (int k0 = 0; k0 < K; k0 += 64) {
    body(0, k0);
    body(1, k0 + 32);
  }

  // epilogue: C/D layout col = lane&15, row = quad*4 + reg (m89/m91 verified)
#pragma unroll
  for (int j = 0; j < 4; ++j) {
    int col = nBase + wn * 64 + j * 16 + l15;
    bool cv = col < Nlog;
    float bv = cv ? bias[col] : 0.f;
#pragma unroll
    for (int i = 0; i < 4; ++i) {
      int row0 = mBase + wm * 64 + i * 16 + quad * 4;
#pragma unroll
      for (int r = 0; r < 4; ++r) {
        float v = acc[i][j][r] + bv;
        size_t idx = (size_t)(row0 + r) * ldc + col;
        if constexpr (EPI == 0) {
          v = cv ? fmaxf(v, 0.f) : 0.f;
          ((_Float16*)Cv)[idx] = (_Float16)v;
        } else if constexpr (EPI == 1) {
          ((float*)Cv)[idx] = v;
        } else {
          ((float*)Cv)[idx] = 1.f / (1.f + __expf(-v));
        }
      }
    }
  }
}

// ---------------------------------------------------------------------------
// rho/logs/std: one wave per row, two dot products over h1[row, 0:400].
// ---------------------------------------------------------------------------
__global__ __launch_bounds__(256) void head_k(
    const _Float16* __restrict__ h1p,
    const float* __restrict__ w22, const float* __restrict__ b22,
    const float* __restrict__ w23, const float* __restrict__ b23,
    float* __restrict__ rho, float* __restrict__ logs, float* __restrict__ stdb)
{
  int lane = threadIdx.x & 63;
  int row  = blockIdx.x * 4 + (threadIdx.x >> 6);
  int kk = lane * 8;
  float s22 = 0.f, s23 = 0.f;
  if (kk < HLOG) {
    f16x8 h = *(const f16x8*)&h1p[(size_t)row * HP + kk];
    f32x4 wa = *(const f32x4*)&w22[kk];
    f32x4 wb = *(const f32x4*)&w22[kk + 4];
    f32x4 va = *(const f32x4*)&w23[kk];
    f32x4 vb = *(const f32x4*)&w23[kk + 4];
#pragma unroll
    for (int j = 0; j < 4; ++j) {
      float hv = (float)h[j];
      s22 += hv * wa[j]; s23 += hv * va[j];
    }
#pragma unroll
    for (int j = 0; j < 4; ++j) {
      float hv = (float)h[4 + j];
      s22 += hv * wb[j]; s23 += hv * vb[j];
    }
  }
#pragma unroll
  for (int d = 32; d > 0; d >>= 1) {
    s22 += __shfl_xor(s22, d);
    s23 += __shfl_xor(s23, d);
  }
  if (lane == 0) {
    rho[row] = tanhf(s22 + b22[0]);
    float lg = s23 + b23[0];
    logs[row] = lg;
    stdb[row] = expf(0.5f * lg);  // sqrt(exp(logs))
  }
}

// ---------------------------------------------------------------------------
// z = cumsum(eps*std) + mu; one wave per row; fp16 output.
// ---------------------------------------------------------------------------
__global__ __launch_bounds__(256) void zscan_k(
    const float* __restrict__ eps, const float* __restrict__ mu,
    const float* __restrict__ stdb, _Float16* __restrict__ zA)
{
  int lane = threadIdx.x & 63;
  int row  = blockIdx.x * 4 + (threadIdx.x >> 6);
  int j0 = lane * 8;
  float s = stdb[row];
  const float* er = eps + (size_t)row * ZD + j0;
  f32x4 e0 = *(const f32x4*)er;
  f32x4 e1 = *(const f32x4*)(er + 4);
  float v[8];
  v[0] = e0[0] * s;
  v[1] = v[0] + e0[1] * s;
  v[2] = v[1] + e0[2] * s;
  v[3] = v[2] + e0[3] * s;
  v[4] = v[3] + e1[0] * s;
  v[5] = v[4] + e1[1] * s;
  v[6] = v[5] + e1[2] * s;
  v[7] = v[6] + e1[3] * s;
  float tot = v[7];
  float inc = tot;
#pragma unroll
  for (int d = 1; d < 64; d <<= 1) {
    float t = __shfl_up(inc, d);
    if (lane >= d) inc += t;
  }
  float off = inc - tot;  // exclusive prefix over lanes
  const float* mr = mu + (size_t)row * ZD + j0;
  f32x4 m0 = *(const f32x4*)mr;
  f32x4 m1 = *(const f32x4*)(mr + 4);
  f16x8 zv;
#pragma unroll
  for (int j = 0; j < 8; ++j) {
    float mv = (j < 4) ? m0[j] : m1[j - 4];
    zv[j] = (_Float16)(off + v[j] + mv);
  }
  *(f16x8*)&zA[(size_t)row * ZD + j0] = zv;
}

// ---------------------------------------------------------------------------
extern "C" void kernel_launch(void* const* d_in, const int* in_sizes, int n_in,
                              void* d_out, int out_size, void* d_ws, size_t ws_size,
                              hipStream_t stream) {
  (void)in_sizes; (void)n_in; (void)out_size; (void)ws_size;
  const float* x   = (const float*)d_in[0];
  const float* eps = (const float*)d_in[1];
  const float* W1  = (const float*)d_in[2];
  const float* b1  = (const float*)d_in[3];
  const float* W21 = (const float*)d_in[4];
  const float* b21 = (const float*)d_in[5];
  const float* W22 = (const float*)d_in[6];
  const float* b22 = (const float*)d_in[7];
  const float* W23 = (const float*)d_in[8];
  const float* b23 = (const float*)d_in[9];
  const float* W3  = (const float*)d_in[10];
  const float* b3  = (const float*)d_in[11];
  const float* W4  = (const float*)d_in[12];
  const float* b4  = (const float*)d_in[13];
  float* out = (float*)d_out;
  char*  ws  = (char*)d_ws;

  _Float16* W1t  = (_Float16*)(ws + O_W1T);
  _Float16* W21t = (_Float16*)(ws + O_W21T);
  _Float16* W3t  = (_Float16*)(ws + O_W3T);
  _Float16* W4t  = (_Float16*)(ws + O_W4T);
  _Float16* h1p  = (_Float16*)(ws + O_H1P);
  _Float16* zA   = (_Float16*)(ws + O_ZA);
  float*    stdb = (float*)(ws + O_STD);
  _Float16* h3p  = h1p;  // h1 dead after zscan; reuse for h3

  pack_all<<<4608, 256, 0, stream>>>(W1, W21, W3, W4, W1t, W21t, W3t, W4t);
  // h1 = relu(x @ W1 + b1)  [16384 x 512 padded f16]
  gemm_k<1, 0><<<dim3(4, 128), 256, 0, stream>>>(x, W1t, b1, h1p, HLOG, DDIM, DDIM, HP);
  // rho, logs, std
  head_k<<<4096, 256, 0, stream>>>(h1p, W22, b22, W23, b23,
                                   out + RHO_OFF, out + LOGS_OFF, stdb);
  // mu = h1 @ W21 + b21 -> d_out (fp32)
  gemm_k<0, 1><<<dim3(4, 128), 256, 0, stream>>>(h1p, W21t, b21, out + MU_OFF, ZD, HP, HP, ZD);
  // z = cumsum(eps*std) + mu (fp16)
  zscan_k<<<4096, 256, 0, stream>>>(eps, out + MU_OFF, stdb, zA);
  // h3 = relu(z @ W3 + b3)
  gemm_k<0, 0><<<dim3(4, 128), 256, 0, stream>>>(zA, W3t, b3, h3p, HLOG, ZD, ZD, HP);
  // recon = sigmoid(h3 @ W4 + b4) -> d_out (fp32)
  gemm_k<0, 2><<<dim3(32, 128), 256, 0, stream>>>(h3p, W4t, b4, out, DDIM, HP, HP, DDIM);
}

// Round 2
// 766.057 us; speedup vs baseline: 1.0542x; 1.0028x over previous
//
#include <hip/hip_runtime.h>
#include <hip/hip_bf16.h>
#include <math.h>

// ---------------------------------------------------------------------------
// RhoVanillaVAE forward on gfx950.
// B=16384, DATA_DIM=4096, Z=512, H=400 (padded to 512 everywhere).
// R2: all GEMMs in fp16 (mfma_f32_16x16x32_f16).
// R3: double-buffered prefetch K-loop + XCD-chunked block swizzle
//     (FETCH 529->148MB, GEMM1 253->198us).
// R4: GEMM1 was LDS-port-BW-bound: fp32 A tile = 48KB/block-iter of the
//     72KB LDS traffic. Now A is reg-staged to fp16 (global f32x4 loads
//     issued before the MFMA block, cvt+ds_write_b128 after it, T14 split).
//     LDS per CU-iter 144KB -> 96KB; frag path uniform f16 for both variants.
// Pipeline: pack weights (fp16, transposed [N][K]) -> GEMM1 (x fp32 -> relu h1 f16)
// -> head matvec (rho/logs/std) -> GEMM2 (mu fp32) -> zscan (cumsum -> z f16)
// -> GEMM3 (relu h3 f16) -> GEMM4 (sigmoid recon fp32).
// GEMM core: 128x128 block tile, 4 waves, 4x4x(16x16x32) MFMA frags per wave,
// BK=32, global_load_lds(16B) staging for f16 operands with XOR chunk swizzle
// so frag ds_read_b128s hit all 8 bank-groups evenly.
// ---------------------------------------------------------------------------

using f16x8 = __attribute__((ext_vector_type(8))) _Float16;
using f32x4 = __attribute__((ext_vector_type(4))) float;

#define TB   16384
#define DDIM 4096
#define ZD   512
#define HP   512   // padded H
#define HLOG 400

static constexpr size_t MU_OFF   = (size_t)TB * DDIM;          // 67108864
static constexpr size_t RHO_OFF  = MU_OFF + (size_t)TB * ZD;   // 75497472
static constexpr size_t LOGS_OFF = RHO_OFF + TB;               // 75513856

// workspace byte offsets
static constexpr size_t O_W1T  = 0;                                  // 512*4096*2 = 4 MiB
static constexpr size_t O_W21T = O_W1T  + (size_t)HP * DDIM * 2;
static constexpr size_t O_W3T  = O_W21T + (size_t)HP * HP * 2;
static constexpr size_t O_W4T  = O_W3T  + (size_t)HP * HP * 2;
static constexpr size_t O_H1P  = O_W4T  + (size_t)DDIM * HP * 2;
static constexpr size_t O_ZA   = O_H1P  + (size_t)TB * HP * 2;
static constexpr size_t O_STD  = O_ZA   + (size_t)TB * ZD * 2;
// end ~ 41 MiB

__device__ __forceinline__ void async_load16(const void* g, void* l) {
  __builtin_amdgcn_global_load_lds(
      (const __attribute__((address_space(1))) unsigned int*)g,
      (__attribute__((address_space(3))) unsigned int*)l, 16, 0, 0);
}

// ---------------------------------------------------------------------------
// Weight pack: dst[n*ds + k] = (k<R && n<C) ? (fp16)src[k*C+n] : 0
// Jobs selected by blockIdx.x range (single launch).
// ---------------------------------------------------------------------------
__global__ __launch_bounds__(256) void pack_all(
    const float* __restrict__ W1, const float* __restrict__ W21,
    const float* __restrict__ W3, const float* __restrict__ W4,
    _Float16* __restrict__ W1t, _Float16* __restrict__ W21t,
    _Float16* __restrict__ W3t, _Float16* __restrict__ W4t)
{
  __shared__ float T[32][33];
  int bx = blockIdx.x;
  const float* src; _Float16* dst; int R, C, ds, tk;
  if (bx < 2048)      { src = W1;  dst = W1t;  R = 4096; C = 400;  ds = 4096; tk = 128; }
  else if (bx < 2304) { src = W21; dst = W21t; R = 400;  C = 512;  ds = 512;  tk = 16; bx -= 2048; }
  else if (bx < 2560) { src = W3;  dst = W3t;  R = 512;  C = 400;  ds = 512;  tk = 16; bx -= 2304; }
  else                { src = W4;  dst = W4t;  R = 400;  C = 4096; ds = 512;  tk = 16; bx -= 2560; }
  int tki = bx % tk, tni = bx / tk;
  int tid = threadIdx.x;
#pragma unroll
  for (int it = 0; it < 4; ++it) {
    int idx = it * 256 + tid;
    int i = idx >> 5, j = idx & 31;
    int k = tki * 32 + i, n = tni * 32 + j;
    float val = 0.f;
    if (k < R && n < C) val = src[(size_t)k * C + n];
    T[i][j] = val;
  }
  __syncthreads();
#pragma unroll
  for (int it = 0; it < 4; ++it) {
    int idx = it * 256 + tid;
    int i = idx >> 5, j = idx & 31;
    int n = tni * 32 + i, k = tki * 32 + j;
    dst[(size_t)n * ds + k] = (_Float16)T[j][i];
  }
}

// ---------------------------------------------------------------------------
// GEMM: C[M x Npad] = A[M x K] @ Bt[Npad x K]^T, M mult of 128, Npad mult of
// 128, K mult of 64. AF32: A is fp32 in global, reg-staged to fp16 in LDS.
// EPI 0: relu -> fp16 (cols >= Nlog forced to 0); 1: +bias -> fp32;
// 2: sigmoid -> fp32.
// Double-buffered: tile k+1 staged while tile k computes; one barrier/iter.
// ---------------------------------------------------------------------------
template <int AF32, int EPI>
__global__ __launch_bounds__(256, AF32 ? 1 : 2) void gemm_k(
    const void* __restrict__ Av, const _Float16* __restrict__ Bt,
    const float* __restrict__ bias, void* __restrict__ Cv,
    int Nlog, int K, int lda, int ldc)
{
  __shared__ _Float16 Bs[2][128 * 32];
  __shared__ _Float16 As[2][128 * 32];

  const int tid  = threadIdx.x;
  const int lane = tid & 63;
  const int wave = tid >> 6;
  const int quad = lane >> 4;
  const int l15  = lane & 15;
  const int wm   = wave >> 1;
  const int wn   = wave & 1;

  // XCD-chunked swizzle: consecutive dispatch ids round-robin XCDs; remap so
  // each XCD owns a contiguous sb-range (all n-blocks of a contiguous m-range
  // -> A-panel fetched into ONE L2). Valid since all grids here are %8==0.
  const int gx  = gridDim.x;
  const int nwg = gx * gridDim.y;
  const int lb  = blockIdx.y * gx + blockIdx.x;
  int sb = lb;
  if ((nwg & 7) == 0) sb = (lb & 7) * (nwg >> 3) + (lb >> 3);
  const int mBase = (sb / gx) * 128;
  const int nBase = (sb % gx) * 128;

  const float*    Af = (const float*)Av;
  const _Float16* Ah = (const _Float16*)Av;

  f32x4 acc[4][4];
#pragma unroll
  for (int i = 0; i < 4; ++i)
#pragma unroll
    for (int j = 0; j < 4; ++j)
      acc[i][j] = (f32x4){0.f, 0.f, 0.f, 0.f};

  // stage B tile [128 n][32 k] f16 via global_load_lds (wave-uniform dest
  // base + lane*16B); chunk (16B = 8 f16) XOR-swizzled by (n>>1)&3.
  auto stageB = [&](int buf, int k0) {
#pragma unroll
    for (int is = 0; is < 2; ++is) {
      int f = is * 256 + tid;
      int n = f >> 2, p = f & 3;
      int c = p ^ ((n >> 1) & 3);
      async_load16(Bt + (size_t)(nBase + n) * K + k0 + c * 8,
                   &Bs[buf][(is * 256 + wave * 64) * 8]);
    }
  };
  // stage A tile (f16 source) same pattern.
  auto stageA_h = [&](int buf, int k0) {
#pragma unroll
    for (int is = 0; is < 2; ++is) {
      int f = is * 256 + tid;
      int m = f >> 2, p = f & 3;
      int c = p ^ ((m >> 1) & 3);
      async_load16(Ah + (size_t)(mBase + m) * lda + k0 + c * 8,
                   &As[buf][(is * 256 + wave * 64) * 8]);
    }
  };

  // A fp32 reg-staging: each thread owns chunk-slots f = tid and 256+tid
  // (row m = f>>2, slot p = f&3, global chunk c = p^((m>>1)&3) = 8 floats).
  // Load 2x f32x4 per slot; later cvt to f16x8 and ds_write_b128 at slot f.
  f32x4 au0, av0, au1, av1;
  auto loadA_f32 = [&](int k0) {
    {
      int f = tid, m = f >> 2, p = f & 3;
      int c = p ^ ((m >> 1) & 3);
      const float* g = Af + (size_t)(mBase + m) * lda + k0 + c * 8;
      au0 = *(const f32x4*)g; av0 = *(const f32x4*)(g + 4);
    }
    {
      int f = 256 + tid, m = f >> 2, p = f & 3;
      int c = p ^ ((m >> 1) & 3);
      const float* g = Af + (size_t)(mBase + m) * lda + k0 + c * 8;
      au1 = *(const f32x4*)g; av1 = *(const f32x4*)(g + 4);
    }
  };
  auto writeA_f16 = [&](int buf) {
    {
      int f = tid;
      f16x8 w;
      w[0] = (_Float16)au0[0]; w[1] = (_Float16)au0[1];
      w[2] = (_Float16)au0[2]; w[3] = (_Float16)au0[3];
      w[4] = (_Float16)av0[0]; w[5] = (_Float16)av0[1];
      w[6] = (_Float16)av0[2]; w[7] = (_Float16)av0[3];
      *(f16x8*)&As[buf][f * 8] = w;
    }
    {
      int f = 256 + tid;
      f16x8 w;
      w[0] = (_Float16)au1[0]; w[1] = (_Float16)au1[1];
      w[2] = (_Float16)au1[2]; w[3] = (_Float16)au1[3];
      w[4] = (_Float16)av1[0]; w[5] = (_Float16)av1[1];
      w[6] = (_Float16)av1[2]; w[7] = (_Float16)av1[3];
      *(f16x8*)&As[buf][f * 8] = w;
    }
  };

  // one K-step: prefetch (kk+32) into buf^1 (B via global_load_lds; A via
  // regs if fp32), compute tile (kk) from buf, then (AF32) cvt+ds_write the
  // A regs into buf^1 AFTER the MFMAs (T14 split: global latency hidden
  // under the MFMA block). Single __syncthreads at end: its implicit
  // vmcnt(0)+lgkmcnt(0) drain lands after the compute covered the latency,
  // and orders buf^1 writes / buf reads across waves.
  auto body = [&](int buf, int kk) {
    const bool pf = (kk + 32 < K);
    if (pf) {
      stageB(buf ^ 1, kk + 32);
      if constexpr (AF32) loadA_f32(kk + 32);
      else                stageA_h(buf ^ 1, kk + 32);
    }

    f16x8 a[4], b[4];
#pragma unroll
    for (int t = 0; t < 4; ++t) {
      int n = wn * 64 + t * 16 + l15;
      b[t] = *(const f16x8*)&Bs[buf][n * 32 + ((quad ^ ((n >> 1) & 3)) * 8)];
    }
#pragma unroll
    for (int t = 0; t < 4; ++t) {
      int m = wm * 64 + t * 16 + l15;
      a[t] = *(const f16x8*)&As[buf][m * 32 + ((quad ^ ((m >> 1) & 3)) * 8)];
    }
#pragma unroll
    for (int i = 0; i < 4; ++i)
#pragma unroll
      for (int j = 0; j < 4; ++j)
        acc[i][j] = __builtin_amdgcn_mfma_f32_16x16x32_f16(a[i], b[j], acc[i][j], 0, 0, 0);

    if constexpr (AF32) {
      if (pf) writeA_f16(buf ^ 1);
    }
    __syncthreads();
  };

  // prologue: fill buf 0.
  stageB(0, 0);
  if constexpr (AF32) { loadA_f32(0); writeA_f16(0); }
  else                stageA_h(0, 0);
  __syncthreads();

  // K is a multiple of 64 for every call site (4096 or 512) -> unroll x2 so
  // the buffer index is a compile-time constant after inlining.
  for (int k0 = 0; k0 < K; k0 += 64) {
    body(0, k0);
    body(1, k0 + 32);
  }

  // epilogue: C/D layout col = lane&15, row = quad*4 + reg (m89/m91 verified)
#pragma unroll
  for (int j = 0; j < 4; ++j) {
    int col = nBase + wn * 64 + j * 16 + l15;
    bool cv = col < Nlog;
    float bv = cv ? bias[col] : 0.f;
#pragma unroll
    for (int i = 0; i < 4; ++i) {
      int row0 = mBase + wm * 64 + i * 16 + quad * 4;
#pragma unroll
      for (int r = 0; r < 4; ++r) {
        float v = acc[i][j][r] + bv;
        size_t idx = (size_t)(row0 + r) * ldc + col;
        if constexpr (EPI == 0) {
          v = cv ? fmaxf(v, 0.f) : 0.f;
          ((_Float16*)Cv)[idx] = (_Float16)v;
        } else if constexpr (EPI == 1) {
          ((float*)Cv)[idx] = v;
        } else {
          ((float*)Cv)[idx] = 1.f / (1.f + __expf(-v));
        }
      }
    }
  }
}

// ---------------------------------------------------------------------------
// rho/logs/std: one wave per row, two dot products over h1[row, 0:400].
// ---------------------------------------------------------------------------
__global__ __launch_bounds__(256) void head_k(
    const _Float16* __restrict__ h1p,
    const float* __restrict__ w22, const float* __restrict__ b22,
    const float* __restrict__ w23, const float* __restrict__ b23,
    float* __restrict__ rho, float* __restrict__ logs, float* __restrict__ stdb)
{
  int lane = threadIdx.x & 63;
  int row  = blockIdx.x * 4 + (threadIdx.x >> 6);
  int kk = lane * 8;
  float s22 = 0.f, s23 = 0.f;
  if (kk < HLOG) {
    f16x8 h = *(const f16x8*)&h1p[(size_t)row * HP + kk];
    f32x4 wa = *(const f32x4*)&w22[kk];
    f32x4 wb = *(const f32x4*)&w22[kk + 4];
    f32x4 va = *(const f32x4*)&w23[kk];
    f32x4 vb = *(const f32x4*)&w23[kk + 4];
#pragma unroll
    for (int j = 0; j < 4; ++j) {
      float hv = (float)h[j];
      s22 += hv * wa[j]; s23 += hv * va[j];
    }
#pragma unroll
    for (int j = 0; j < 4; ++j) {
      float hv = (float)h[4 + j];
      s22 += hv * wb[j]; s23 += hv * vb[j];
    }
  }
#pragma unroll
  for (int d = 32; d > 0; d >>= 1) {
    s22 += __shfl_xor(s22, d);
    s23 += __shfl_xor(s23, d);
  }
  if (lane == 0) {
    rho[row] = tanhf(s22 + b22[0]);
    float lg = s23 + b23[0];
    logs[row] = lg;
    stdb[row] = expf(0.5f * lg);  // sqrt(exp(logs))
  }
}

// ---------------------------------------------------------------------------
// z = cumsum(eps*std) + mu; one wave per row; fp16 output.
// ---------------------------------------------------------------------------
__global__ __launch_bounds__(256) void zscan_k(
    const float* __restrict__ eps, const float* __restrict__ mu,
    const float* __restrict__ stdb, _Float16* __restrict__ zA)
{
  int lane = threadIdx.x & 63;
  int row  = blockIdx.x * 4 + (threadIdx.x >> 6);
  int j0 = lane * 8;
  float s = stdb[row];
  const float* er = eps + (size_t)row * ZD + j0;
  f32x4 e0 = *(const f32x4*)er;
  f32x4 e1 = *(const f32x4*)(er + 4);
  float v[8];
  v[0] = e0[0] * s;
  v[1] = v[0] + e0[1] * s;
  v[2] = v[1] + e0[2] * s;
  v[3] = v[2] + e0[3] * s;
  v[4] = v[3] + e1[0] * s;
  v[5] = v[4] + e1[1] * s;
  v[6] = v[5] + e1[2] * s;
  v[7] = v[6] + e1[3] * s;
  float tot = v[7];
  float inc = tot;
#pragma unroll
  for (int d = 1; d < 64; d <<= 1) {
    float t = __shfl_up(inc, d);
    if (lane >= d) inc += t;
  }
  float off = inc - tot;  // exclusive prefix over lanes
  const float* mr = mu + (size_t)row * ZD + j0;
  f32x4 m0 = *(const f32x4*)mr;
  f32x4 m1 = *(const f32x4*)(mr + 4);
  f16x8 zv;
#pragma unroll
  for (int j = 0; j < 8; ++j) {
    float mv = (j < 4) ? m0[j] : m1[j - 4];
    zv[j] = (_Float16)(off + v[j] + mv);
  }
  *(f16x8*)&zA[(size_t)row * ZD + j0] = zv;
}

// ---------------------------------------------------------------------------
extern "C" void kernel_launch(void* const* d_in, const int* in_sizes, int n_in,
                              void* d_out, int out_size, void* d_ws, size_t ws_size,
                              hipStream_t stream) {
  (void)in_sizes; (void)n_in; (void)out_size; (void)ws_size;
  const float* x   = (const float*)d_in[0];
  const float* eps = (const float*)d_in[1];
  const float* W1  = (const float*)d_in[2];
  const float* b1  = (const float*)d_in[3];
  const float* W21 = (const float*)d_in[4];
  const float* b21 = (const float*)d_in[5];
  const float* W22 = (const float*)d_in[6];
  const float* b22 = (const float*)d_in[7];
  const float* W23 = (const float*)d_in[8];
  const float* b23 = (const float*)d_in[9];
  const float* W3  = (const float*)d_in[10];
  const float* b3  = (const float*)d_in[11];
  const float* W4  = (const float*)d_in[12];
  const float* b4  = (const float*)d_in[13];
  float* out = (float*)d_out;
  char*  ws  = (char*)d_ws;

  _Float16* W1t  = (_Float16*)(ws + O_W1T);
  _Float16* W21t = (_Float16*)(ws + O_W21T);
  _Float16* W3t  = (_Float16*)(ws + O_W3T);
  _Float16* W4t  = (_Float16*)(ws + O_W4T);
  _Float16* h1p  = (_Float16*)(ws + O_H1P);
  _Float16* zA   = (_Float16*)(ws + O_ZA);
  float*    stdb = (float*)(ws + O_STD);
  _Float16* h3p  = h1p;  // h1 dead after zscan; reuse for h3

  pack_all<<<4608, 256, 0, stream>>>(W1, W21, W3, W4, W1t, W21t, W3t, W4t);
  // h1 = relu(x @ W1 + b1)  [16384 x 512 padded f16]
  gemm_k<1, 0><<<dim3(4, 128), 256, 0, stream>>>(x, W1t, b1, h1p, HLOG, DDIM, DDIM, HP);
  // rho, logs, std
  head_k<<<4096, 256, 0, stream>>>(h1p, W22, b22, W23, b23,
                                   out + RHO_OFF, out + LOGS_OFF, stdb);
  // mu = h1 @ W21 + b21 -> d_out (fp32)
  gemm_k<0, 1><<<dim3(4, 128), 256, 0, stream>>>(h1p, W21t, b21, out + MU_OFF, ZD, HP, HP, ZD);
  // z = cumsum(eps*std) + mu (fp16)
  zscan_k<<<4096, 256, 0, stream>>>(eps, out + MU_OFF, stdb, zA);
  // h3 = relu(z @ W3 + b3)
  gemm_k<0, 0><<<dim3(4, 128), 256, 0, stream>>>(zA, W3t, b3, h3p, HLOG, ZD, ZD, HP);
  // recon = sigmoid(h3 @ W4 + b4) -> d_out (fp32)
  gemm_k<0, 2><<<dim3(32, 128), 256, 0, stream>>>(h3p, W4t, b4, out, DDIM, HP, HP, DDIM);
}